// Round 6
// baseline (271.130 us; speedup 1.0000x reference)
//
#include <hip/hip_runtime.h>

// ---------------------------------------------------------------------------
// Round 11 (resubmit after infra failure): uniform work + full-tile load
// cover. Round-10 showed occupancy decay (50%->~1 block/CU tail): block work
// was prop. to qt. Now 512 blocks x 4 waves, each handles q-tile pair
// (15-p, p) = 36 k-tiles UNIFORM. V is double-buffered again -> ONE
// vmcnt(0)+barrier per tile, loads issued at tile top get the whole tile
// (~700cy) of cover. LDS 48KB (3 blocks/CU cap, grid 2/CU). Keeps: cvt_pk
// pack, persistent-zero C, hoisted Ps pointers, setprio, XCD head mapping.
// B=4, S=2048, NH=16, DH=64, E=1024. fp32 I/O, bf16 compute, fp32 accum.
// ---------------------------------------------------------------------------

typedef __attribute__((ext_vector_type(8))) short short8;
typedef __attribute__((ext_vector_type(4))) float floatx4;

#define SCL 0.1803368801111244f   // (1/8) * log2(e), folded into Q projection

__device__ __forceinline__ unsigned short f2bf(float f) {
  unsigned int x = __float_as_uint(f);
  x += 0x7fffu + ((x >> 16) & 1u);   // RNE
  return (unsigned short)(x >> 16);
}

__device__ __forceinline__ void gload_lds16(const unsigned short* g, unsigned short* lds) {
  __builtin_amdgcn_global_load_lds(
      (const __attribute__((address_space(1))) void*)g,
      (__attribute__((address_space(3))) void*)lds, 16, 0, 0);
}

// ---------------- fused prep: cvt_x + W_QKV transpose + W_O transpose ------
__global__ __launch_bounds__(256) void prep_kernel(
    const float* __restrict__ X,  unsigned short* __restrict__ Xb,
    const float* __restrict__ Wq, const float* __restrict__ Wk,
    const float* __restrict__ Wv, unsigned short* __restrict__ Bt,
    const float* __restrict__ Wo, unsigned short* __restrict__ Wt)
{
  __shared__ unsigned short T[64 * 72];
  const int bid = blockIdx.x, t = threadIdx.x;
  if (bid < 8192) {                                  // ---- x fp32 -> bf16
    int idx = ((bid << 8) + t) << 2;
    float4 f = *(const float4*)(X + idx);
    unsigned short u[4] = { f2bf(f.x), f2bf(f.y), f2bf(f.z), f2bf(f.w) };
    *(uint2*)(Xb + idx) = *(uint2*)u;
  } else if (bid < 8960) {                           // ---- W_{Q,K,V} transpose
    int b2 = bid - 8192;
    int e0 = (b2 & 15) << 6, nn = (b2 >> 4) & 15, proj = b2 >> 8;
    const float* W = (proj == 0) ? Wq : (proj == 1) ? Wk : Wv;
    const float* src = W + ((size_t)nn << 16) + ((size_t)e0 << 6);
#pragma unroll
    for (int rnd = 0; rnd < 4; ++rnd) {
      int off = (rnd << 10) + (t << 2);
      float4 f = *(const float4*)(src + off);
      int r = off >> 6, h = off & 63;
      T[r * 72 + h]     = f2bf(f.x);
      T[r * 72 + h + 1] = f2bf(f.y);
      T[r * 72 + h + 2] = f2bf(f.z);
      T[r * 72 + h + 3] = f2bf(f.w);
    }
    __syncthreads();
    const int h = t >> 2, ck = t & 3;
    size_t orow = ((size_t)((proj << 10) + (nn << 6) + h) << 10) + e0 + (ck << 4);
#pragma unroll
    for (int g = 0; g < 2; ++g) {
      unsigned short v[8];
#pragma unroll
      for (int j = 0; j < 8; ++j) v[j] = T[((ck << 4) + (g << 3) + j) * 72 + h];
      *(int4*)(Bt + orow + (g << 3)) = *(int4*)v;
    }
  } else {                                           // ---- W_O transpose
    int b2 = bid - 8960;
    int e0 = (b2 & 15) << 6, k0 = (b2 >> 4) << 6;
#pragma unroll
    for (int rnd = 0; rnd < 4; ++rnd) {
      int r = (rnd << 4) + (t >> 4);
      int c = (t & 15) << 2;
      float4 f = *(const float4*)(Wo + ((size_t)(k0 + r) << 10) + e0 + c);
      T[r * 72 + c]     = f2bf(f.x);
      T[r * 72 + c + 1] = f2bf(f.y);
      T[r * 72 + c + 2] = f2bf(f.z);
      T[r * 72 + c + 3] = f2bf(f.w);
    }
    __syncthreads();
    const int i = t >> 2, ck = t & 3;
    size_t orow = ((size_t)(e0 + i) << 10) + k0 + (ck << 4);
#pragma unroll
    for (int g = 0; g < 2; ++g) {
      unsigned short v[8];
#pragma unroll
      for (int j = 0; j < 8; ++j) v[j] = T[((ck << 4) + (g << 3) + j) * 72 + i];
      *(int4*)(Wt + orow + (g << 3)) = *(int4*)v;
    }
  }
}

// ---------------- 128x128 MFMA GEMM, BK=64 (round-5, kept) -----------------
template <int MODE>
__global__ __launch_bounds__(256) void gemm128_kernel(
    const unsigned short* __restrict__ A,
    const unsigned short* __restrict__ Bt,
    const float* __restrict__ b0, const float* __restrict__ b1,
    const float* __restrict__ b2,
    unsigned short* __restrict__ Oq, unsigned short* __restrict__ Ok,
    unsigned short* __restrict__ Ov, float* __restrict__ Of)
{
  const int K = 1024;
  __shared__ __align__(16) unsigned short As[8192];   // [128][64] swizzled
  __shared__ __align__(16) unsigned short Bs[8192];
  const int tid = threadIdx.x;
  const int l   = tid & 63, w = tid >> 6;
  const int l15 = l & 15,  lg = l >> 4;
  const int mo  = (w >> 1) << 6, no = (w & 1) << 6;
  const int m0  = blockIdx.y << 7, n0 = blockIdx.x << 7;
  const int srow = l >> 3;
  const int gblk = ((l & 7) ^ srow) << 3;
  const int rsw  = l15 & 7;

  floatx4 acc[4][4];
#pragma unroll
  for (int i = 0; i < 4; ++i)
#pragma unroll
    for (int j = 0; j < 4; ++j) acc[i][j] = (floatx4){0.f, 0.f, 0.f, 0.f};

  for (int k0 = 0; k0 < K; k0 += 64) {
    __syncthreads();
#pragma unroll
    for (int s = 0; s < 4; ++s) {
      const int br = (s << 5) + (w << 3);
      gload_lds16(A  + (size_t)(m0 + br + srow) * K + k0 + gblk, &As[br << 6]);
      gload_lds16(Bt + (size_t)(n0 + br + srow) * K + k0 + gblk, &Bs[br << 6]);
    }
    __syncthreads();
#pragma unroll
    for (int kh = 0; kh < 2; ++kh) {
      const int bo = (((kh << 2) + lg) ^ rsw) << 3;
      short8 af[4], bf[4];
#pragma unroll
      for (int mc = 0; mc < 4; ++mc)
        af[mc] = *(const short8*)&As[((mo + (mc << 4) + l15) << 6) + bo];
#pragma unroll
      for (int nc = 0; nc < 4; ++nc)
        bf[nc] = *(const short8*)&Bs[((no + (nc << 4) + l15) << 6) + bo];
#pragma unroll
      for (int mc = 0; mc < 4; ++mc)
#pragma unroll
        for (int nc = 0; nc < 4; ++nc)
          acc[mc][nc] = __builtin_amdgcn_mfma_f32_16x16x32_bf16(af[mc], bf[nc], acc[mc][nc], 0, 0, 0);
    }
  }

#pragma unroll
  for (int nc = 0; nc < 4; ++nc) {
    int c = n0 + no + (nc << 4) + l15;
    if (MODE == 1) {
      float bv = b0[c];
#pragma unroll
      for (int mc = 0; mc < 4; ++mc)
#pragma unroll
        for (int r = 0; r < 4; ++r) {
          int m = m0 + mo + (mc << 4) + (lg << 2) + r;
          Of[((size_t)m << 10) + c] = acc[mc][nc][r] + bv;
        }
    } else {
      int proj = c >> 10, cc = c & 1023;         // wave-uniform
      int hn = cc >> 6, h = cc & 63;
      const float* bp = (proj == 0) ? b0 : (proj == 1) ? b1 : b2;
      float bv = bp[cc];
      float sc = (proj == 0) ? SCL : 1.0f;
      if (proj < 2) {
        unsigned short* O = (proj == 0) ? Oq : Ok;
#pragma unroll
        for (int mc = 0; mc < 4; ++mc)
#pragma unroll
          for (int r = 0; r < 4; ++r) {
            int m = m0 + mo + (mc << 4) + (lg << 2) + r;
            int bb = m >> 11, ss = m & 2047;
            O[((((size_t)(bb << 4) + hn) << 11) + ss) * 64 + h] = f2bf((acc[mc][nc][r] + bv) * sc);
          }
      } else {                                   // V transposed: Vt[b][n][d][s]
#pragma unroll
        for (int mc = 0; mc < 4; ++mc) {
          int m = m0 + mo + (mc << 4) + (lg << 2);
          int bb = m >> 11, ss = m & 2047;
          unsigned short p0 = f2bf(acc[mc][nc][0] + bv);
          unsigned short p1 = f2bf(acc[mc][nc][1] + bv);
          unsigned short p2 = f2bf(acc[mc][nc][2] + bv);
          unsigned short p3 = f2bf(acc[mc][nc][3] + bv);
          uint2 pk;
          pk.x = (unsigned int)p0 | ((unsigned int)p1 << 16);
          pk.y = (unsigned int)p2 | ((unsigned int)p3 << 16);
          *(uint2*)&Ov[((((size_t)(bb << 4) + hn) << 6) + h) * 2048 + ss] = pk;
        }
      }
    }
  }
}

// ---------------- MFMA flash attention v10: uniform pairs, 1 fence/tile ----
// 512 blocks x 256 threads (4 waves x 32 q-rows = 128-row q-tile).
// Block p (p = x>>6, 0..7) processes q-tile pair (15-p, p) -> 36 k-tiles
// UNIFORM across all blocks. head = x&63 -> XCD = head%8 (8 heads x 512KB
// K/V = 4MB = L2/XCD). K and V both double-buffered; K/V[t+1] issued at
// tile top; single vmcnt(0)+s_barrier at tile end (full-tile load cover).
// LDS 48KB -> 3 blocks/CU capacity (grid 2/CU -> steady 8 waves/CU).
__global__ __launch_bounds__(256, 3) void flash10_kernel(
    const unsigned short* __restrict__ Q,   // [B,N,S,D], pre-scaled by SCL
    const unsigned short* __restrict__ K,   // [B,N,S,D]
    const unsigned short* __restrict__ Vt,  // [B,N,D,S]
    unsigned short* __restrict__ Z)         // [B,S,N*D]
{
  __shared__ __align__(16) unsigned short Ks[8192];   // 2 x [64 key][64 d] swz
  __shared__ __align__(16) unsigned short Vs[8192];   // 2 x [64 d][64 key] swz
  __shared__ __align__(16) unsigned short Ps[8192];   // 4 waves x [32 q][64 k] swz

  const int tid = threadIdx.x;
  const int l   = tid & 63, w = tid >> 6;             // w in {0,1,2,3}
  const int l15 = l & 15,  lg = l >> 4;
  const int x    = blockIdx.x;
  const int pidx = x >> 6;                            // pair index 0..7
  const int head = x & 63;
  const int n = head & 15, b = head >> 4;
  const size_t hoff = (size_t)head << 17;
  const unsigned short* Qh = Q + hoff;
  const unsigned short* Kh = K + hoff;
  const unsigned short* Vh = Vt + hoff;
  unsigned short* Psw = Ps + (w << 11);

  const int srow8 = l >> 3;
  const int sblk8 = ((l & 7) ^ srow8) << 3;
  const int swz   = l15 & 7;
  const int bo0   = (lg ^ swz) << 3;
  const int bo1   = ((4 + lg) ^ swz) << 3;

  // ---- staging base pointers (hoisted) ----
  const unsigned short* gK = Kh + (size_t)(((w << 4) + srow8) << 6) + sblk8;
  const unsigned short* gV = Vh + (size_t)(((w << 4) + srow8) << 11) + sblk8;
  unsigned short* ldsK0 = &Ks[w << 10];               // + (buf<<12), +512 for seg1
  unsigned short* ldsV0 = &Vs[w << 10];

  // ---- Ps pointers (hoisted; row&7 == swz) ----
  uint2* pw[2][4];
  const short8* pr[2][2];
#pragma unroll
  for (int qc = 0; qc < 2; ++qc) {
    const int rbase = ((qc << 4) + l15) << 6;
#pragma unroll
    for (int mc = 0; mc < 4; ++mc)
      pw[qc][mc] = (uint2*)&Psw[rbase + (((((mc << 1) + (lg >> 1)) ^ swz) << 3) + ((lg & 1) << 2))];
#pragma unroll
    for (int kc = 0; kc < 2; ++kc)
      pr[qc][kc] = (const short8*)&Psw[rbase + ((((kc << 2) + lg) ^ swz) << 3)];
  }

  short8 onef;
#pragma unroll
  for (int i = 0; i < 8; ++i) onef[i] = (short)0x3F80;   // bf16 1.0

  // persistent zero C-operand (laundered so it is never re-materialized)
  floatx4 z4 = (floatx4){0.f, 0.f, 0.f, 0.f};
  asm volatile("" : "+v"(z4));

  // ---- prologue: stage K/V tile 0 (of half 0) into buffer 0 ----
  gload_lds16(gK,         ldsK0);
  gload_lds16(gK + 512,   ldsK0 + 512);
  gload_lds16(gV,         ldsV0);
  gload_lds16(gV + 16384, ldsV0 + 512);
  asm volatile("s_waitcnt vmcnt(0)" ::: "memory");
  __builtin_amdgcn_s_barrier();

  int buf = 0;
  for (int half = 0; half < 2; ++half) {
    const int qt  = half ? pidx : (15 - pidx);         // heavy tile first
    const int q0w = (qt << 7) + (w << 5);              // wave's 32 rows

    short8 qf[2][2];
#pragma unroll
    for (int qc = 0; qc < 2; ++qc)
#pragma unroll
      for (int dh = 0; dh < 2; ++dh)
        qf[qc][dh] = *(const short8*)(Qh + (size_t)(q0w + (qc << 4) + l15) * 64 + (dh << 5) + (lg << 3));

    floatx4 acc_o[2][4], acc_l[2];
#pragma unroll
    for (int qc = 0; qc < 2; ++qc) {
      acc_l[qc] = (floatx4){0.f, 0.f, 0.f, 0.f};
#pragma unroll
      for (int dc = 0; dc < 4; ++dc) acc_o[qc][dc] = (floatx4){0.f, 0.f, 0.f, 0.f};
    }

    const int nkt = (qt << 1) + 2;                     // 64-key tiles
    for (int kt = 0; kt < nkt; ++kt) {
      const int k0 = kt << 6;

      // ---- issue next tile's K/V into buf^1 (full-tile latency cover) ----
      const int nk0 = (kt + 1 < nkt) ? ((kt + 1) << 6) : (half == 0 ? 0 : -1);
      if (nk0 >= 0) {
        const int nb = (buf ^ 1) << 12;
        const unsigned short* pK = gK + ((size_t)nk0 << 6);
        gload_lds16(pK,       ldsK0 + nb);
        gload_lds16(pK + 512, ldsK0 + nb + 512);
        const unsigned short* pV = gV + nk0;
        gload_lds16(pV,         ldsV0 + nb);
        gload_lds16(pV + 16384, ldsV0 + nb + 512);
      }

      const bool active = (k0 <= q0w + 31);
      if (active) {
        const int cb = buf << 12;

        // ---- S^T[key][q] = K * Q^T (first MFMA uses persistent zero C) ----
        floatx4 s0[4], s1[4];
        __builtin_amdgcn_s_setprio(1);
#pragma unroll
        for (int mc = 0; mc < 4; ++mc) {
          short8 ak = *(const short8*)&Ks[cb + (((mc << 4) + l15) << 6) + bo0];
          s0[mc] = __builtin_amdgcn_mfma_f32_16x16x32_bf16(ak, qf[0][0], z4, 0, 0, 0);
          s1[mc] = __builtin_amdgcn_mfma_f32_16x16x32_bf16(ak, qf[1][0], z4, 0, 0, 0);
        }
#pragma unroll
        for (int mc = 0; mc < 4; ++mc) {
          short8 ak = *(const short8*)&Ks[cb + (((mc << 4) + l15) << 6) + bo1];
          s0[mc] = __builtin_amdgcn_mfma_f32_16x16x32_bf16(ak, qf[0][1], s0[mc], 0, 0, 0);
          s1[mc] = __builtin_amdgcn_mfma_f32_16x16x32_bf16(ak, qf[1][1], s1[mc], 0, 0, 0);
        }
        __builtin_amdgcn_s_setprio(0);

        // ---- p = 2^s; mask only on diagonal tiles; cvt_pk pack ----
        const bool needmask = (k0 + 63 > q0w);
#pragma unroll
        for (int qc = 0; qc < 2; ++qc) {
          const int qg = q0w + (qc << 4) + l15;
#pragma unroll
          for (int mc = 0; mc < 4; ++mc) {
            float p[4];
#pragma unroll
            for (int r = 0; r < 4; ++r) {
              float e = exp2f(qc ? s1[mc][r] : s0[mc][r]);
              if (needmask) {
                int key = k0 + (mc << 4) + (lg << 2) + r;
                e = (key > qg) ? 0.f : e;
              }
              p[r] = e;
            }
            uint2 pk;
            asm("v_cvt_pk_bf16_f32 %0, %1, %2" : "=v"(pk.x) : "v"(p[0]), "v"(p[1]));
            asm("v_cvt_pk_bf16_f32 %0, %1, %2" : "=v"(pk.y) : "v"(p[2]), "v"(p[3]));
            *pw[qc][mc] = pk;
          }
        }

        // ---- PV: O += P*V ; l += P*ones ----
        short8 pa[2][2];
#pragma unroll
        for (int qc = 0; qc < 2; ++qc)
#pragma unroll
          for (int kc = 0; kc < 2; ++kc)
            pa[qc][kc] = *pr[qc][kc];
        __builtin_amdgcn_s_setprio(1);
#pragma unroll
        for (int kc = 0; kc < 2; ++kc) {
          const int bo = kc ? bo1 : bo0;
#pragma unroll
          for (int dc = 0; dc < 4; ++dc) {
            short8 vb = *(const short8*)&Vs[cb + (((dc << 4) + l15) << 6) + bo];
            acc_o[0][dc] = __builtin_amdgcn_mfma_f32_16x16x32_bf16(pa[0][kc], vb, acc_o[0][dc], 0, 0, 0);
            acc_o[1][dc] = __builtin_amdgcn_mfma_f32_16x16x32_bf16(pa[1][kc], vb, acc_o[1][dc], 0, 0, 0);
          }
          acc_l[0] = __builtin_amdgcn_mfma_f32_16x16x32_bf16(pa[0][kc], onef, acc_l[0], 0, 0, 0);
          acc_l[1] = __builtin_amdgcn_mfma_f32_16x16x32_bf16(pa[1][kc], onef, acc_l[1], 0, 0, 0);
        }
        __builtin_amdgcn_s_setprio(0);
      }

      // ---- tile fence: next-tile loads landed; all waves done with buf ----
      asm volatile("s_waitcnt vmcnt(0)" ::: "memory");
      __builtin_amdgcn_s_barrier();
      buf ^= 1;
    }

    // ---- epilogue: Z = O / l ----
#pragma unroll
    for (int qc = 0; qc < 2; ++qc) {
      floatx4 inv;
#pragma unroll
      for (int r = 0; r < 4; ++r) inv[r] = 1.f / acc_l[qc][r];
#pragma unroll
      for (int dc = 0; dc < 4; ++dc)
#pragma unroll
        for (int r = 0; r < 4; ++r) {
          int qg = q0w + (qc << 4) + (lg << 2) + r;
          Z[(((size_t)b << 11) + qg) * 1024 + (n << 6) + (dc << 4) + l15] =
              f2bf(acc_o[qc][dc][r] * inv[r]);
        }
    }
  }
}

// ---------------------------------------------------------------------------
extern "C" void kernel_launch(void* const* d_in, const int* in_sizes, int n_in,
                              void* d_out, int out_size, void* d_ws, size_t ws_size,
                              hipStream_t stream) {
  const float* x   = (const float*)d_in[0];
  const float* W_Q = (const float*)d_in[1];
  const float* b_Q = (const float*)d_in[2];
  const float* W_K = (const float*)d_in[3];
  const float* b_K = (const float*)d_in[4];
  const float* W_V = (const float*)d_in[5];
  const float* b_V = (const float*)d_in[6];
  const float* W_O = (const float*)d_in[7];
  const float* b_O = (const float*)d_in[8];
  float* out = (float*)d_out;

  unsigned short* ws    = (unsigned short*)d_ws;
  unsigned short* BtQKV = ws;                        // [3072][1024]
  unsigned short* Wo_t  = BtQKV + (3u << 20);        // [1024][1024]
  unsigned short* Xb    = Wo_t + (1u << 20);         // [8192][1024]
  unsigned short* Qb    = Xb + (8u << 20);           // [B,N,S,D]
  unsigned short* Kb    = Qb + (8u << 20);
  unsigned short* Vtb   = Kb + (8u << 20);           // [B,N,D,S]
  unsigned short* Zb    = Vtb + (8u << 20);          // [B,S,N*D]

  prep_kernel<<<9216, 256, 0, stream>>>(x, Xb, W_Q, W_K, W_V, BtQKV, W_O, Wo_t);

  gemm128_kernel<0><<<dim3(24, 64), 256, 0, stream>>>(
      Xb, BtQKV, b_Q, b_K, b_V, Qb, Kb, Vtb, nullptr);

  flash10_kernel<<<512, 256, 0, stream>>>(Qb, Kb, Vtb, Zb);

  gemm128_kernel<1><<<dim3(8, 64), 256, 0, stream>>>(
      Zb, Wo_t, b_O, nullptr, nullptr, nullptr, nullptr, nullptr, out);
}

// Round 7
// 267.781 us; speedup vs baseline: 1.0125x; 1.0125x over previous
//
#include <hip/hip_runtime.h>

// ---------------------------------------------------------------------------
// Round 12: flash ported to the m214-verified 32x32 in-register-softmax
// structure. Swapped QK^T (mfma(K,Q), 32x32x16) puts each lane's P-row
// lane-local: P->PV hand-off is 16 cvt_pk_bf16_f32 + 8 permlane32_swap in
// REGISTERS -- the Ps LDS bounce (8 writes + 4 reads + 2 lgkm chains/tile)
// and its 16KB are gone. LDS 32KB (K+V dbuf) -> 5 blocks/CU cap; grid keeps
// flash9's 1024-block LPT (qt=15-(x>>6)); one vmcnt(0)+barrier per tile.
// B=4, S=2048, NH=16, DH=64, E=1024. fp32 I/O, bf16 compute, fp32 accum.
// ---------------------------------------------------------------------------

typedef __attribute__((ext_vector_type(8))) short short8;
typedef __attribute__((ext_vector_type(4))) float floatx4;
typedef __attribute__((ext_vector_type(16))) float floatx16;

#define SCL 0.1803368801111244f   // (1/8) * log2(e), folded into Q projection

__device__ __forceinline__ unsigned short f2bf(float f) {
  unsigned int x = __float_as_uint(f);
  x += 0x7fffu + ((x >> 16) & 1u);   // RNE
  return (unsigned short)(x >> 16);
}

__device__ __forceinline__ void gload_lds16(const unsigned short* g, unsigned short* lds) {
  __builtin_amdgcn_global_load_lds(
      (const __attribute__((address_space(1))) void*)g,
      (__attribute__((address_space(3))) void*)lds, 16, 0, 0);
}

// ---------------- fused prep: cvt_x + W_QKV transpose + W_O transpose ------
__global__ __launch_bounds__(256) void prep_kernel(
    const float* __restrict__ X,  unsigned short* __restrict__ Xb,
    const float* __restrict__ Wq, const float* __restrict__ Wk,
    const float* __restrict__ Wv, unsigned short* __restrict__ Bt,
    const float* __restrict__ Wo, unsigned short* __restrict__ Wt)
{
  __shared__ unsigned short T[64 * 72];
  const int bid = blockIdx.x, t = threadIdx.x;
  if (bid < 8192) {                                  // ---- x fp32 -> bf16
    int idx = ((bid << 8) + t) << 2;
    float4 f = *(const float4*)(X + idx);
    unsigned short u[4] = { f2bf(f.x), f2bf(f.y), f2bf(f.z), f2bf(f.w) };
    *(uint2*)(Xb + idx) = *(uint2*)u;
  } else if (bid < 8960) {                           // ---- W_{Q,K,V} transpose
    int b2 = bid - 8192;
    int e0 = (b2 & 15) << 6, nn = (b2 >> 4) & 15, proj = b2 >> 8;
    const float* W = (proj == 0) ? Wq : (proj == 1) ? Wk : Wv;
    const float* src = W + ((size_t)nn << 16) + ((size_t)e0 << 6);
#pragma unroll
    for (int rnd = 0; rnd < 4; ++rnd) {
      int off = (rnd << 10) + (t << 2);
      float4 f = *(const float4*)(src + off);
      int r = off >> 6, h = off & 63;
      T[r * 72 + h]     = f2bf(f.x);
      T[r * 72 + h + 1] = f2bf(f.y);
      T[r * 72 + h + 2] = f2bf(f.z);
      T[r * 72 + h + 3] = f2bf(f.w);
    }
    __syncthreads();
    const int h = t >> 2, ck = t & 3;
    size_t orow = ((size_t)((proj << 10) + (nn << 6) + h) << 10) + e0 + (ck << 4);
#pragma unroll
    for (int g = 0; g < 2; ++g) {
      unsigned short v[8];
#pragma unroll
      for (int j = 0; j < 8; ++j) v[j] = T[((ck << 4) + (g << 3) + j) * 72 + h];
      *(int4*)(Bt + orow + (g << 3)) = *(int4*)v;
    }
  } else {                                           // ---- W_O transpose
    int b2 = bid - 8960;
    int e0 = (b2 & 15) << 6, k0 = (b2 >> 4) << 6;
#pragma unroll
    for (int rnd = 0; rnd < 4; ++rnd) {
      int r = (rnd << 4) + (t >> 4);
      int c = (t & 15) << 2;
      float4 f = *(const float4*)(Wo + ((size_t)(k0 + r) << 10) + e0 + c);
      T[r * 72 + c]     = f2bf(f.x);
      T[r * 72 + c + 1] = f2bf(f.y);
      T[r * 72 + c + 2] = f2bf(f.z);
      T[r * 72 + c + 3] = f2bf(f.w);
    }
    __syncthreads();
    const int i = t >> 2, ck = t & 3;
    size_t orow = ((size_t)(e0 + i) << 10) + k0 + (ck << 4);
#pragma unroll
    for (int g = 0; g < 2; ++g) {
      unsigned short v[8];
#pragma unroll
      for (int j = 0; j < 8; ++j) v[j] = T[((ck << 4) + (g << 3) + j) * 72 + i];
      *(int4*)(Wt + orow + (g << 3)) = *(int4*)v;
    }
  }
}

// ---------------- 128x128 MFMA GEMM, BK=64 (round-5, kept) -----------------
template <int MODE>
__global__ __launch_bounds__(256) void gemm128_kernel(
    const unsigned short* __restrict__ A,
    const unsigned short* __restrict__ Bt,
    const float* __restrict__ b0, const float* __restrict__ b1,
    const float* __restrict__ b2,
    unsigned short* __restrict__ Oq, unsigned short* __restrict__ Ok,
    unsigned short* __restrict__ Ov, float* __restrict__ Of)
{
  const int K = 1024;
  __shared__ __align__(16) unsigned short As[8192];   // [128][64] swizzled
  __shared__ __align__(16) unsigned short Bs[8192];
  const int tid = threadIdx.x;
  const int l   = tid & 63, w = tid >> 6;
  const int l15 = l & 15,  lg = l >> 4;
  const int mo  = (w >> 1) << 6, no = (w & 1) << 6;
  const int m0  = blockIdx.y << 7, n0 = blockIdx.x << 7;
  const int srow = l >> 3;
  const int gblk = ((l & 7) ^ srow) << 3;
  const int rsw  = l15 & 7;

  floatx4 acc[4][4];
#pragma unroll
  for (int i = 0; i < 4; ++i)
#pragma unroll
    for (int j = 0; j < 4; ++j) acc[i][j] = (floatx4){0.f, 0.f, 0.f, 0.f};

  for (int k0 = 0; k0 < K; k0 += 64) {
    __syncthreads();
#pragma unroll
    for (int s = 0; s < 4; ++s) {
      const int br = (s << 5) + (w << 3);
      gload_lds16(A  + (size_t)(m0 + br + srow) * K + k0 + gblk, &As[br << 6]);
      gload_lds16(Bt + (size_t)(n0 + br + srow) * K + k0 + gblk, &Bs[br << 6]);
    }
    __syncthreads();
#pragma unroll
    for (int kh = 0; kh < 2; ++kh) {
      const int bo = (((kh << 2) + lg) ^ rsw) << 3;
      short8 af[4], bf[4];
#pragma unroll
      for (int mc = 0; mc < 4; ++mc)
        af[mc] = *(const short8*)&As[((mo + (mc << 4) + l15) << 6) + bo];
#pragma unroll
      for (int nc = 0; nc < 4; ++nc)
        bf[nc] = *(const short8*)&Bs[((no + (nc << 4) + l15) << 6) + bo];
#pragma unroll
      for (int mc = 0; mc < 4; ++mc)
#pragma unroll
        for (int nc = 0; nc < 4; ++nc)
          acc[mc][nc] = __builtin_amdgcn_mfma_f32_16x16x32_bf16(af[mc], bf[nc], acc[mc][nc], 0, 0, 0);
    }
  }

#pragma unroll
  for (int nc = 0; nc < 4; ++nc) {
    int c = n0 + no + (nc << 4) + l15;
    if (MODE == 1) {
      float bv = b0[c];
#pragma unroll
      for (int mc = 0; mc < 4; ++mc)
#pragma unroll
        for (int r = 0; r < 4; ++r) {
          int m = m0 + mo + (mc << 4) + (lg << 2) + r;
          Of[((size_t)m << 10) + c] = acc[mc][nc][r] + bv;
        }
    } else {
      int proj = c >> 10, cc = c & 1023;         // wave-uniform
      int hn = cc >> 6, h = cc & 63;
      const float* bp = (proj == 0) ? b0 : (proj == 1) ? b1 : b2;
      float bv = bp[cc];
      float sc = (proj == 0) ? SCL : 1.0f;
      if (proj < 2) {
        unsigned short* O = (proj == 0) ? Oq : Ok;
#pragma unroll
        for (int mc = 0; mc < 4; ++mc)
#pragma unroll
          for (int r = 0; r < 4; ++r) {
            int m = m0 + mo + (mc << 4) + (lg << 2) + r;
            int bb = m >> 11, ss = m & 2047;
            O[((((size_t)(bb << 4) + hn) << 11) + ss) * 64 + h] = f2bf((acc[mc][nc][r] + bv) * sc);
          }
      } else {                                   // V transposed: Vt[b][n][d][s]
#pragma unroll
        for (int mc = 0; mc < 4; ++mc) {
          int m = m0 + mo + (mc << 4) + (lg << 2);
          int bb = m >> 11, ss = m & 2047;
          unsigned short p0 = f2bf(acc[mc][nc][0] + bv);
          unsigned short p1 = f2bf(acc[mc][nc][1] + bv);
          unsigned short p2 = f2bf(acc[mc][nc][2] + bv);
          unsigned short p3 = f2bf(acc[mc][nc][3] + bv);
          uint2 pk;
          pk.x = (unsigned int)p0 | ((unsigned int)p1 << 16);
          pk.y = (unsigned int)p2 | ((unsigned int)p3 << 16);
          *(uint2*)&Ov[((((size_t)(bb << 4) + hn) << 6) + h) * 2048 + ss] = pk;
        }
      }
    }
  }
}

// ---------------- MFMA flash attention v11: 32x32, in-register softmax -----
// 1024 blocks x 256 threads (4 waves x 32 q-rows = 128-row q-tile).
// qt = 15-(x>>6) LPT; head = x&63 -> XCD = head%8 (8 heads x 512KB = L2/XCD).
// Per wave-tile (32q x 64k): QK^T = 8 mfma_32x32x16 (A=K, B=Q^T -> lane
// holds P[q=lane&31][16 keys]); exp2; cvt_pk+permlane32_swap assembles PV
// A-frags in registers (no Ps LDS); PV = 8 O-mfma + 4 l-mfma (ones trick).
// K,V double-buffered (32KB LDS); one vmcnt(0)+s_barrier per k-tile.
__global__ __launch_bounds__(256, 4) void flash11_kernel(
    const unsigned short* __restrict__ Q,   // [B,N,S,D], pre-scaled by SCL
    const unsigned short* __restrict__ K,   // [B,N,S,D]
    const unsigned short* __restrict__ Vt,  // [B,N,D,S]
    unsigned short* __restrict__ Z)         // [B,S,N*D]
{
  __shared__ __align__(16) unsigned short Ks[8192];   // 2 x [64 key][64 d] swz
  __shared__ __align__(16) unsigned short Vs[8192];   // 2 x [64 d][64 key] swz

  const int tid = threadIdx.x;
  const int l   = tid & 63, w = tid >> 6;             // w in {0,1,2,3}
  const int l31 = l & 31,  hi = l >> 5;
  const int x    = blockIdx.x;
  const int qt   = 15 - (x >> 6);                     // 128-row q-tile, LPT
  const int head = x & 63;
  const int n = head & 15, b = head >> 4;
  const size_t hoff = (size_t)head << 17;
  const unsigned short* Qh = Q + hoff;
  const unsigned short* Kh = K + hoff;
  const unsigned short* Vh = Vt + hoff;

  const int srow8 = l >> 3;
  const int sblk8 = ((l & 7) ^ srow8) << 3;
  const int r7    = l31 & 7;
  const int rowoff = l31 << 6;                        // shorts, within 64x64

  // koff[c]: swizzled 16B-block offset for d-block (K read) / key-block (V
  // read) = block (2c+hi) ^ (row&7), row&7 == l31&7 for all our rows.
  int koff[4];
#pragma unroll
  for (int c = 0; c < 4; ++c) koff[c] = ((((c << 1) + hi) ^ r7) << 3);

  // ---- staging base pointers (proven flash9/10 paths) ----
  const unsigned short* gK = Kh + (size_t)(((w << 4) + srow8) << 6) + sblk8;
  const unsigned short* gV = Vh + (size_t)(((w << 4) + srow8) << 11) + sblk8;
  unsigned short* ldsK0 = &Ks[w << 10];               // + (buf<<12), +512 seg1
  unsigned short* ldsV0 = &Vs[w << 10];

  short8 onef;
#pragma unroll
  for (int i = 0; i < 8; ++i) onef[i] = (short)0x3F80;   // bf16 1.0

  // persistent zero C-operand (16 regs, laundered against rematerialization)
  floatx16 z16;
#pragma unroll
  for (int i = 0; i < 16; ++i) z16[i] = 0.f;
  asm volatile("" : "+v"(z16));

  const int q0w = (qt << 7) + (w << 5);               // wave's 32 rows
  const int qg  = q0w + l31;                          // this lane's q row

  // Q fragments: qf[c] = Q[q=qg][d = c*16 + hi*8 .. +7]
  short8 qf[4];
#pragma unroll
  for (int c = 0; c < 4; ++c)
    qf[c] = *(const short8*)(Qh + (size_t)qg * 64 + (c << 4) + (hi << 3));

  floatx16 acc_o[2], acc_l;
#pragma unroll
  for (int i = 0; i < 16; ++i) { acc_o[0][i] = 0.f; acc_o[1][i] = 0.f; acc_l[i] = 0.f; }

  // ---- prologue: stage K/V tile 0 into buffer 0 ----
  gload_lds16(gK,         ldsK0);
  gload_lds16(gK + 512,   ldsK0 + 512);
  gload_lds16(gV,         ldsV0);
  gload_lds16(gV + 16384, ldsV0 + 512);
  asm volatile("s_waitcnt vmcnt(0)" ::: "memory");
  __builtin_amdgcn_s_barrier();

  int buf = 0;
  const int nkt = (qt << 1) + 2;                      // 64-key tiles
  for (int kt = 0; kt < nkt; ++kt) {
    const int k0 = kt << 6;

    // ---- issue next tile's K/V into buf^1 (full-tile latency cover) ----
    if (kt + 1 < nkt) {
      const int nk0 = (kt + 1) << 6;
      const int nb = (buf ^ 1) << 12;
      const unsigned short* pK = gK + ((size_t)nk0 << 6);
      gload_lds16(pK,       ldsK0 + nb);
      gload_lds16(pK + 512, ldsK0 + nb + 512);
      const unsigned short* pV = gV + nk0;
      gload_lds16(pV,         ldsV0 + nb);
      gload_lds16(pV + 16384, ldsV0 + nb + 512);
    }

    if (k0 <= q0w + 31) {                             // wave-uniform skip
      const int cb = buf << 12;
      const bool needmask = (k0 + 63 > q0w);

#pragma unroll
      for (int kc2 = 0; kc2 < 2; ++kc2) {             // 32-key halves
        const int kbase = cb + (kc2 << 11) + rowoff;  // K rows kc2*32 + l31

        // ---- S^T[key][q]: 4 mfma over d-chunks; C=persistent zero ----
        floatx16 s;
        __builtin_amdgcn_s_setprio(1);
        {
          short8 ak = *(const short8*)&Ks[kbase + koff[0]];
          s = __builtin_amdgcn_mfma_f32_32x32x16_bf16(ak, qf[0], z16, 0, 0, 0);
        }
#pragma unroll
        for (int c = 1; c < 4; ++c) {
          short8 ak = *(const short8*)&Ks[kbase + koff[c]];
          s = __builtin_amdgcn_mfma_f32_32x32x16_bf16(ak, qf[c], s, 0, 0, 0);
        }
        __builtin_amdgcn_s_setprio(0);

        // ---- p = 2^s with causal mask (key = k0+kc2*32+(r&3)+8(r>>2)+4hi)
        float p[16];
#pragma unroll
        for (int r = 0; r < 16; ++r) {
          float e = exp2f(s[r]);
          if (needmask) {
            int key = k0 + (kc2 << 5) + (r & 3) + ((r >> 2) << 3) + (hi << 2);
            e = (key > qg) ? 0.f : e;
          }
          p[r] = e;
        }

        // ---- per 16-key chunk: in-register pack + swap, then PV ----
#pragma unroll
        for (int cc = 0; cc < 2; ++cc) {
          const int o = cc << 3;
          unsigned int w0, w1, w2, w3;
          asm("v_cvt_pk_bf16_f32 %0, %1, %2" : "=v"(w0) : "v"(p[o + 0]), "v"(p[o + 1]));
          asm("v_cvt_pk_bf16_f32 %0, %1, %2" : "=v"(w2) : "v"(p[o + 4]), "v"(p[o + 5]));
          asm volatile("v_permlane32_swap_b32 %0, %1" : "+v"(w0), "+v"(w2));
          asm("v_cvt_pk_bf16_f32 %0, %1, %2" : "=v"(w1) : "v"(p[o + 2]), "v"(p[o + 3]));
          asm("v_cvt_pk_bf16_f32 %0, %1, %2" : "=v"(w3) : "v"(p[o + 6]), "v"(p[o + 7]));
          asm volatile("v_permlane32_swap_b32 %0, %1" : "+v"(w1), "+v"(w3));
          union { unsigned int u[4]; short8 v; } pu;
          pu.u[0] = w0; pu.u[1] = w1; pu.u[2] = w2; pu.u[3] = w3;
          const short8 pa = pu.v;                    // P[q=qg][k chunk, 8 keys]

          const int c = (kc2 << 1) + cc;             // key-block-of-16 index
          __builtin_amdgcn_s_setprio(1);
          short8 vb0 = *(const short8*)&Vs[cb + rowoff + koff[c]];
          acc_o[0] = __builtin_amdgcn_mfma_f32_32x32x16_bf16(pa, vb0, acc_o[0], 0, 0, 0);
          short8 vb1 = *(const short8*)&Vs[cb + rowoff + 2048 + koff[c]];
          acc_o[1] = __builtin_amdgcn_mfma_f32_32x32x16_bf16(pa, vb1, acc_o[1], 0, 0, 0);
          acc_l = __builtin_amdgcn_mfma_f32_32x32x16_bf16(pa, onef, acc_l, 0, 0, 0);
          __builtin_amdgcn_s_setprio(0);
        }
      }
    }

    // ---- tile fence: next-tile loads landed; all waves done with buf ----
    asm volatile("s_waitcnt vmcnt(0)" ::: "memory");
    __builtin_amdgcn_s_barrier();
    buf ^= 1;
  }

  // ---- epilogue: Z = O / l ; row q = q0w + (r&3)+8(r>>2)+4hi, col d ----
  float inv[16];
#pragma unroll
  for (int r = 0; r < 16; ++r) inv[r] = 1.f / acc_l[r];
#pragma unroll
  for (int dc = 0; dc < 2; ++dc)
#pragma unroll
    for (int r = 0; r < 16; ++r) {
      int qrow = q0w + (r & 3) + ((r >> 2) << 3) + (hi << 2);
      Z[(((size_t)b << 11) + qrow) * 1024 + (n << 6) + (dc << 5) + l31] =
          f2bf(acc_o[dc][r] * inv[r]);
    }
}

// ---------------------------------------------------------------------------
extern "C" void kernel_launch(void* const* d_in, const int* in_sizes, int n_in,
                              void* d_out, int out_size, void* d_ws, size_t ws_size,
                              hipStream_t stream) {
  const float* x   = (const float*)d_in[0];
  const float* W_Q = (const float*)d_in[1];
  const float* b_Q = (const float*)d_in[2];
  const float* W_K = (const float*)d_in[3];
  const float* b_K = (const float*)d_in[4];
  const float* W_V = (const float*)d_in[5];
  const float* b_V = (const float*)d_in[6];
  const float* W_O = (const float*)d_in[7];
  const float* b_O = (const float*)d_in[8];
  float* out = (float*)d_out;

  unsigned short* ws    = (unsigned short*)d_ws;
  unsigned short* BtQKV = ws;                        // [3072][1024]
  unsigned short* Wo_t  = BtQKV + (3u << 20);        // [1024][1024]
  unsigned short* Xb    = Wo_t + (1u << 20);         // [8192][1024]
  unsigned short* Qb    = Xb + (8u << 20);           // [B,N,S,D]
  unsigned short* Kb    = Qb + (8u << 20);
  unsigned short* Vtb   = Kb + (8u << 20);           // [B,N,D,S]
  unsigned short* Zb    = Vtb + (8u << 20);          // [B,S,N*D]

  prep_kernel<<<9216, 256, 0, stream>>>(x, Xb, W_Q, W_K, W_V, BtQKV, W_O, Wo_t);

  gemm128_kernel<0><<<dim3(24, 64), 256, 0, stream>>>(
      Xb, BtQKV, b_Q, b_K, b_V, Qb, Kb, Vtb, nullptr);

  flash11_kernel<<<1024, 256, 0, stream>>>(Qb, Kb, Vtb, Zb);

  gemm128_kernel<1><<<dim3(8, 64), 256, 0, stream>>>(
      Zb, Wo_t, b_O, nullptr, nullptr, nullptr, nullptr, nullptr, out);
}